// Round 1
// 161.158 us; speedup vs baseline: 1.0002x; 1.0002x over previous
//
#include <hip/hip_runtime.h>
#include <math.h>

// Problem constants (from reference)
#define N_ROWS    16384
#define NC        1000
#define KVAL      5.0f
#define ALPHA     0.025f
#define N_ITER    80
#define MAX_SOLVE 12        // Newton passes; warm-started, early-exits in 1-3
#define EPS_P     1e-6f
#define EPJ       16        // elements per lane: 16*64 = 1024 >= 1000
#define ALN2      0.0173286795139986f   // ALPHA * ln(2)
#define N_ACC     256       // distributed loss accumulators

// R14: occupancy push. Counters (R13): VALUBusy 83-88%, Occupancy 66%
// (= the (64,6) 75% cap minus drain), HBM 4.5%, zero LDS conflicts -> pure
// VALU-issue bound with ~15% idle from exposed latency (wave_sum DPP chains,
// quarter-rate v_log pairs) at only ~5 resident waves/SIMD.
//  1) __launch_bounds__(64,8): actual VGPR use ~50 (R7 compile check) fits
//     the 64-reg cap -> 8 waves/SIMD. Spill tripwire: WRITE_SIZE >> 512 KB.
//  2) Pad-lane poison: cc[15] = -10 on the 24 dead lanes; their v locks at
//     a bitwise-constant negative value, p = relu(v-nu) = 0 forever, never
//     enters s or m. Removes the per-iteration j==15 cndmask. Output is
//     bit-identical to R13 (pads only alter self-compared checksums).
//
// CYCLE DETECTION (R10/R12 lesson): most rows lock into a bitwise period-2
// flush cycle, but a ~3% subpopulation is bitwise period-4 — the warm-start
// recursion nu(t) = f(v(t), nu(t-2)) settles into a 2-cycle on the nu
// odd/even chains (Newton step dithers around the 3e-8 tolerance), so the
// full state only repeats at distance 4. A 2-back-only detector (R6/R9/R12)
// misses them -> those rows run all 80 iters -> long low-occupancy tail.
// A 4-back-only detector (R10) catches everything but adds +2 iters lag on
// the period-2 majority. Fire on EITHER: both break rules are individually
// verified reference-exact (absmax 0.0 in R12 / R10).
//
// R11 lesson: no single-address returning-atomic ticket (serializes ~200 us).
// R7 lesson: state must fit the launch-bounds cap (WRITE_SIZE is the spill
// tripwire). Solver invariants (R4/R5): real-element v in [0.11,0.92] =>
// upper clip never binds, nu* > 0, s(nu)=sum relu(v-nu) convex
// piecewise-linear => warm-started Newton converges globally & monotonically
// after one step.

template <int CTRL>
__device__ __forceinline__ float dpp_add(float x) {
    int t = __builtin_amdgcn_update_dpp(0, __float_as_int(x), CTRL, 0xf, 0xf, true);
    return x + __int_as_float(t);
}

// Full 64-lane sum -> uniform via readlane(63).
__device__ __forceinline__ float wave_sum(float x) {
    x = dpp_add<0x111>(x);  // row_shr:1
    x = dpp_add<0x112>(x);  // row_shr:2
    x = dpp_add<0x114>(x);  // row_shr:4
    x = dpp_add<0x118>(x);  // row_shr:8
    x = dpp_add<0x142>(x);  // row_bcast:15
    x = dpp_add<0x143>(x);  // row_bcast:31 -> lane63 = total
    return __int_as_float(__builtin_amdgcn_readlane(__float_as_int(x), 63));
}

__global__ __launch_bounds__(64, 8) void pgd_kernel(
        const float* __restrict__ x,
        const int*   __restrict__ y,
        double*      __restrict__ acc) {
    const int lane = threadIdx.x;
    const int row  = blockIdx.x;
    const bool valid15 = lane < (NC - 15 * 64);  // lane < 40 for j==15

    const float* __restrict__ xr = x + (size_t)row * NC;
    const int yv = y[row];            // prefetch: independent, schedules early
    const float flane = (float)(lane + 1);   // checksum weight base

    float cc[EPJ];  // ALPHA * normalized logits (pads: poisoned to -10)
    float v[EPJ];   // pre-projection iterate; p == relu(v - nu)

    // ---- load row + sum of squares (L2 normalize) ----
    float ss = 0.f;
#pragma unroll
    for (int j = 0; j < EPJ; ++j) {
        const int e = j * 64 + lane;
        float xv = (e < NC) ? xr[e] : 0.f;
        cc[j] = xv;
        ss += xv * xv;
    }
    ss = wave_sum(ss);
    const float sc = ALPHA / fmaxf(sqrtf(ss), 1e-12f);
#pragma unroll
    for (int j = 0; j < EPJ; ++j) cc[j] *= sc;
    // Pad poison: v_pad' = 0 + cc_pad + ALN2*D0 ~ -9.65 < 0 every iteration
    // (bitwise constant), so p_pad = 0, never counted in s or m. Lets the hot
    // loop run all 64 lanes unmasked.
    if (!valid15) cc[15] = -10.0f;

    // init so relu(v - nu) == p0 = 0.005 exactly (pads: 0)
#pragma unroll
    for (int j = 0; j < EPJ; ++j) v[j] = KVAL / (float)NC;
    if (!valid15) v[15] = 0.f;
    float nu = 0.f;                  // projection shift for current v
    float nu_m1 = 0.f, nu_m2 = 0.f;  // warm-start history

    // fingerprints: fA = 1 check (2 iters) back, fB = 2 checks (4 iters) back
    float fA_nu = -1.f, fA_c1 = 0.f, fA_c2 = 0.f;  int fA_m = -1;
    float fB_nu = -2.f, fB_c1 = 0.f, fB_c2 = 0.f;  int fB_m = -2;

    for (int it = 0; it < N_ITER; ++it) {
        // ---- ascent: p = relu(v-nu); v' = p + alpha*c + aln2*(log2(1-pc)-log2(pc)) ----
#pragma unroll
        for (int j = 0; j < EPJ; ++j) {
            float pj = fmaxf(v[j] - nu, 0.f);
            float pc = fmaxf(pj, EPS_P);
            float d  = __log2f(1.f - pc) - __log2f(pc);
            v[j] = fmaf(ALN2, d, pj + cc[j]);
        }

        // ---- projection: warm-started Newton on convex s(nu)=K ----
        float nu_new = nu_m2;
        int   m_fin  = 0;
        for (int pass = 0; pass < MAX_SOLVE; ++pass) {
            float s = 0.f;
            int   m = 0;
#pragma unroll
            for (int j = 0; j < EPJ; ++j) {
                float t = v[j] - nu_new;
                s += fmaxf(t, 0.f);
                m += (int)__builtin_popcountll(__ballot(t > 0.f));  // slope
            }
            s = wave_sum(s);
            if (m == 0) { nu_new = 0.f; continue; }  // restart below root (s(0)>K)
            m_fin = m;
            float step = (s - KVAL) / (float)m;
            nu_new += step;
            if (fabsf(step) < 3e-8f) break;          // ~1 ULP: converged
        }
        nu_m2 = nu_m1;
        nu_m1 = nu_new;
        nu    = nu_new;   // p_t == relu(v - nu)

        // ---- period-2/4 fingerprint at odd it (completed count even, like 80) ----
        if (it & 1) {
            float c1 = 0.f, c2 = 0.f;
#pragma unroll
            for (int j = 0; j < EPJ; ++j) {
                c1 = fmaf(v[j], cc[j], c1);
                c2 = fmaf(v[j], flane + (float)(j * 64), c2);
            }
            c1 = wave_sum(c1);
            c2 = wave_sum(c2);
            const bool hit2 = (__float_as_int(nu) == __float_as_int(fA_nu)) &&
                              (m_fin == fA_m) &&
                              (__float_as_int(c1) == __float_as_int(fA_c1)) &&
                              (__float_as_int(c2) == __float_as_int(fA_c2));
            const bool hit4 = (__float_as_int(nu) == __float_as_int(fB_nu)) &&
                              (m_fin == fB_m) &&
                              (__float_as_int(c1) == __float_as_int(fB_c1)) &&
                              (__float_as_int(c2) == __float_as_int(fB_c2));
            fB_nu = fA_nu; fB_m = fA_m; fB_c1 = fA_c1; fB_c2 = fA_c2;
            fA_nu = nu;    fA_m = m_fin; fA_c1 = c1;   fA_c2 = c2;
            if (hit2 || hit4) break;   // state == 2 or 4 iterations back
        }
    }

    // ---- pick p[y] = relu(v[y]-nu), loss = -log(p_y + 1e-8) ----
    const int jy = yv >> 6;
    const int ly = yv & 63;
    float sel = 0.f;
#pragma unroll
    for (int j = 0; j < EPJ; ++j) sel = (j == jy) ? v[j] : sel;
    const float vy = __shfl(sel, ly, 64);
    const float py = fminf(fmaxf(vy - nu, 0.f), 1.f);

    if (lane == 0)
        atomicAdd(&acc[row & (N_ACC - 1)], (double)(-logf(py + 1e-8f)));
}

__global__ void finalize_kernel(const double* __restrict__ acc,
                                float* __restrict__ out) {
    const int l = threadIdx.x;      // 64 lanes
    double s = acc[l] + acc[l + 64] + acc[l + 128] + acc[l + 192];
#pragma unroll
    for (int m = 32; m >= 1; m >>= 1) s += __shfl_down(s, m, 64);
    if (l == 0) out[0] = (float)(s / (double)N_ROWS);
}

extern "C" void kernel_launch(void* const* d_in, const int* in_sizes, int n_in,
                              void* d_out, int out_size, void* d_ws, size_t ws_size,
                              hipStream_t stream) {
    const float* x = (const float*)d_in[0];
    const int*   y = (const int*)d_in[1];
    double* acc = (double*)d_ws;

    (void)hipMemsetAsync(acc, 0, N_ACC * sizeof(double), stream);  // ws poisoned 0xAA
    pgd_kernel<<<N_ROWS, 64, 0, stream>>>(x, y, acc);
    finalize_kernel<<<1, 64, 0, stream>>>(acc, (float*)d_out);
}

// Round 2
// 161.123 us; speedup vs baseline: 1.0005x; 1.0002x over previous
//
#include <hip/hip_runtime.h>
#include <math.h>

// Problem constants (from reference)
#define N_ROWS    16384
#define NC        1000
#define KVAL      5.0f
#define ALPHA     0.025f
#define N_ITER    80
#define MAX_SOLVE 12        // Newton passes; warm-started, early-exits in 1-3
#define EPS_P     1e-6f
#define EPJ       16        // elements per lane: 16*64 = 1024 >= 1000
#define ALN2      0.0173286795139986f   // ALPHA * ln(2)
#define N_ACC     256       // distributed loss accumulators
#define ROWS_PER_BLOCK 4    // 4 independent waves per 256-thread workgroup

// R15: workgroup packing for occupancy. R14's A/B killed the launch-bounds
// theory: (64,6)->(64,8) left OccupancyPercent at the same 66-68% and
// VGPR_Count is only 32 -> the register file never capped residency. The
// remaining structural limiter for 16384 single-wave workgroups is the
// per-CU WORKGROUP-slot cap (binds at ~21-24 WGs/CU before the 32-wave cap).
// Fix: 4 rows per 256-thread block, one row per wave, zero LDS / zero
// barriers / zero cross-wave coupling -> 8 WG-slots/CU now hold 32 waves.
// Cost accepted: WG retires when its slowest of 4 rows finishes (small tail
// coupling) vs steady-state issue gain (VALUBusy 88% -> target 93-96%).
// Per-row math is UNTOUCHED -> output bit-identical (absmax 0.0 tripwire).
//
// CYCLE DETECTION (R10/R12 lesson): most rows lock into a bitwise period-2
// flush cycle, but a ~3% subpopulation is bitwise period-4 — the warm-start
// recursion nu(t) = f(v(t), nu(t-2)) settles into a 2-cycle on the nu
// odd/even chains (Newton step dithers around the 3e-8 tolerance), so the
// full state only repeats at distance 4. A 2-back-only detector (R6/R9/R12)
// misses them -> those rows run all 80 iters -> long low-occupancy tail.
// A 4-back-only detector (R10) catches everything but adds +2 iters lag on
// the period-2 majority. Fire on EITHER: both break rules are individually
// verified reference-exact (absmax 0.0 in R12 / R10).
//
// R11 lesson: no single-address returning-atomic ticket (serializes ~200 us).
// R7 lesson: state must fit the launch-bounds cap (WRITE_SIZE is the spill
// tripwire). Solver invariants (R4/R5): real-element v in [0.11,0.92] =>
// upper clip never binds, nu* > 0, s(nu)=sum relu(v-nu) convex
// piecewise-linear => warm-started Newton converges globally & monotonically
// after one step.

template <int CTRL>
__device__ __forceinline__ float dpp_add(float x) {
    int t = __builtin_amdgcn_update_dpp(0, __float_as_int(x), CTRL, 0xf, 0xf, true);
    return x + __int_as_float(t);
}

// Full 64-lane sum -> uniform via readlane(63).
__device__ __forceinline__ float wave_sum(float x) {
    x = dpp_add<0x111>(x);  // row_shr:1
    x = dpp_add<0x112>(x);  // row_shr:2
    x = dpp_add<0x114>(x);  // row_shr:4
    x = dpp_add<0x118>(x);  // row_shr:8
    x = dpp_add<0x142>(x);  // row_bcast:15
    x = dpp_add<0x143>(x);  // row_bcast:31 -> lane63 = total
    return __int_as_float(__builtin_amdgcn_readlane(__float_as_int(x), 63));
}

__global__ __launch_bounds__(64 * ROWS_PER_BLOCK, 8) void pgd_kernel(
        const float* __restrict__ x,
        const int*   __restrict__ y,
        double*      __restrict__ acc) {
    const int lane = threadIdx.x & 63;
    const int row  = blockIdx.x * ROWS_PER_BLOCK + (threadIdx.x >> 6);
    const bool valid15 = lane < (NC - 15 * 64);  // lane < 40 for j==15

    const float* __restrict__ xr = x + (size_t)row * NC;
    const int yv = y[row];            // prefetch: independent, schedules early
    const float flane = (float)(lane + 1);   // checksum weight base

    float cc[EPJ];  // ALPHA * normalized logits (pads: poisoned to -10)
    float v[EPJ];   // pre-projection iterate; p == relu(v - nu)

    // ---- load row + sum of squares (L2 normalize) ----
    float ss = 0.f;
#pragma unroll
    for (int j = 0; j < EPJ; ++j) {
        const int e = j * 64 + lane;
        float xv = (e < NC) ? xr[e] : 0.f;
        cc[j] = xv;
        ss += xv * xv;
    }
    ss = wave_sum(ss);
    const float sc = ALPHA / fmaxf(sqrtf(ss), 1e-12f);
#pragma unroll
    for (int j = 0; j < EPJ; ++j) cc[j] *= sc;
    // Pad poison: v_pad' = 0 + cc_pad + ALN2*D0 ~ -9.65 < 0 every iteration
    // (bitwise constant), so p_pad = 0, never counted in s or m. Lets the hot
    // loop run all 64 lanes unmasked.
    if (!valid15) cc[15] = -10.0f;

    // init so relu(v - nu) == p0 = 0.005 exactly (pads: 0)
#pragma unroll
    for (int j = 0; j < EPJ; ++j) v[j] = KVAL / (float)NC;
    if (!valid15) v[15] = 0.f;
    float nu = 0.f;                  // projection shift for current v
    float nu_m1 = 0.f, nu_m2 = 0.f;  // warm-start history

    // fingerprints: fA = 1 check (2 iters) back, fB = 2 checks (4 iters) back
    float fA_nu = -1.f, fA_c1 = 0.f, fA_c2 = 0.f;  int fA_m = -1;
    float fB_nu = -2.f, fB_c1 = 0.f, fB_c2 = 0.f;  int fB_m = -2;

    for (int it = 0; it < N_ITER; ++it) {
        // ---- ascent: p = relu(v-nu); v' = p + alpha*c + aln2*(log2(1-pc)-log2(pc)) ----
#pragma unroll
        for (int j = 0; j < EPJ; ++j) {
            float pj = fmaxf(v[j] - nu, 0.f);
            float pc = fmaxf(pj, EPS_P);
            float d  = __log2f(1.f - pc) - __log2f(pc);
            v[j] = fmaf(ALN2, d, pj + cc[j]);
        }

        // ---- projection: warm-started Newton on convex s(nu)=K ----
        float nu_new = nu_m2;
        int   m_fin  = 0;
        for (int pass = 0; pass < MAX_SOLVE; ++pass) {
            float s = 0.f;
            int   m = 0;
#pragma unroll
            for (int j = 0; j < EPJ; ++j) {
                float t = v[j] - nu_new;
                s += fmaxf(t, 0.f);
                m += (int)__builtin_popcountll(__ballot(t > 0.f));  // slope
            }
            s = wave_sum(s);
            if (m == 0) { nu_new = 0.f; continue; }  // restart below root (s(0)>K)
            m_fin = m;
            float step = (s - KVAL) / (float)m;
            nu_new += step;
            if (fabsf(step) < 3e-8f) break;          // ~1 ULP: converged
        }
        nu_m2 = nu_m1;
        nu_m1 = nu_new;
        nu    = nu_new;   // p_t == relu(v - nu)

        // ---- period-2/4 fingerprint at odd it (completed count even, like 80) ----
        if (it & 1) {
            float c1 = 0.f, c2 = 0.f;
#pragma unroll
            for (int j = 0; j < EPJ; ++j) {
                c1 = fmaf(v[j], cc[j], c1);
                c2 = fmaf(v[j], flane + (float)(j * 64), c2);
            }
            c1 = wave_sum(c1);
            c2 = wave_sum(c2);
            const bool hit2 = (__float_as_int(nu) == __float_as_int(fA_nu)) &&
                              (m_fin == fA_m) &&
                              (__float_as_int(c1) == __float_as_int(fA_c1)) &&
                              (__float_as_int(c2) == __float_as_int(fA_c2));
            const bool hit4 = (__float_as_int(nu) == __float_as_int(fB_nu)) &&
                              (m_fin == fB_m) &&
                              (__float_as_int(c1) == __float_as_int(fB_c1)) &&
                              (__float_as_int(c2) == __float_as_int(fB_c2));
            fB_nu = fA_nu; fB_m = fA_m; fB_c1 = fA_c1; fB_c2 = fA_c2;
            fA_nu = nu;    fA_m = m_fin; fA_c1 = c1;   fA_c2 = c2;
            if (hit2 || hit4) break;   // state == 2 or 4 iterations back
        }
    }

    // ---- pick p[y] = relu(v[y]-nu), loss = -log(p_y + 1e-8) ----
    const int jy = yv >> 6;
    const int ly = yv & 63;
    float sel = 0.f;
#pragma unroll
    for (int j = 0; j < EPJ; ++j) sel = (j == jy) ? v[j] : sel;
    const float vy = __shfl(sel, ly, 64);
    const float py = fminf(fmaxf(vy - nu, 0.f), 1.f);

    if (lane == 0)
        atomicAdd(&acc[row & (N_ACC - 1)], (double)(-logf(py + 1e-8f)));
}

__global__ void finalize_kernel(const double* __restrict__ acc,
                                float* __restrict__ out) {
    const int l = threadIdx.x;      // 64 lanes
    double s = acc[l] + acc[l + 64] + acc[l + 128] + acc[l + 192];
#pragma unroll
    for (int m = 32; m >= 1; m >>= 1) s += __shfl_down(s, m, 64);
    if (l == 0) out[0] = (float)(s / (double)N_ROWS);
}

extern "C" void kernel_launch(void* const* d_in, const int* in_sizes, int n_in,
                              void* d_out, int out_size, void* d_ws, size_t ws_size,
                              hipStream_t stream) {
    const float* x = (const float*)d_in[0];
    const int*   y = (const int*)d_in[1];
    double* acc = (double*)d_ws;

    (void)hipMemsetAsync(acc, 0, N_ACC * sizeof(double), stream);  // ws poisoned 0xAA
    pgd_kernel<<<N_ROWS / ROWS_PER_BLOCK, 64 * ROWS_PER_BLOCK, 0, stream>>>(x, y, acc);
    finalize_kernel<<<1, 64, 0, stream>>>(acc, (float*)d_out);
}

// Round 3
// 160.198 us; speedup vs baseline: 1.0062x; 1.0058x over previous
//
#include <hip/hip_runtime.h>
#include <math.h>

// Problem constants (from reference)
#define N_ROWS    16384
#define NC        1000
#define KVAL      5.0f
#define ALPHA     0.025f
#define N_ITER    80
#define MAX_SOLVE 12        // Newton passes; warm-started, early-exits in 1-3
#define EPS_P     1e-6f
#define EPJ       16        // elements per lane: 16*64 = 1024 >= 1000
#define ALN2      0.0173286795139986f   // ALPHA * ln(2)
#define ROWS_PER_BLOCK 4    // 4 independent waves per 256-thread workgroup

// R16: dispatch-count A/B. Evidence: R13->R15 improved the pgd dispatch
// 95.3 -> 90.1 us (-5.5%) while harness dur_us moved 161.196 -> 161.123
// (-0.05%), and dur_us is stable to +-0.04 us while kernels vary +-1 us.
// dur_us is therefore NOT tracking the kernel chain — it is pinned by a
// fixed ~161 us quantity. Two candidate models:
//   (a) serialized per-launch overhead (3 dispatches x ~15-20 us + kernel)
//   (b) a fixed harness-side op (input restore) overlapping the chain,
//       dur = max(restore, chain) — chain already below the floor.
// This round discriminates: cut 3 dispatches -> 2 by replacing the atomic
// accumulator (+ its memset) with an unconditionally-written per-row loss
// array (no init needed: every slot written exactly once). pgd math is
// byte-identical; per-row f32 loss values identical; finalize sums them in
// double (reorder vs old 256-slot scheme perturbs the double mean ~1e-12
// relative -> f32 output identical, absmax 0.0 tripwire).
// If dur drops ~15-20 us -> model (a), next step is single-dispatch fusion.
// If dur unchanged -> model (b) confirmed -> harness floor, declare ROOFLINE.
//
// CYCLE DETECTION (R10/R12 lesson): most rows lock into a bitwise period-2
// flush cycle, but a ~3% subpopulation is bitwise period-4 — the warm-start
// recursion nu(t) = f(v(t), nu(t-2)) settles into a 2-cycle on the nu
// odd/even chains (Newton step dithers around the 3e-8 tolerance), so the
// full state only repeats at distance 4. A 2-back-only detector (R6/R9/R12)
// misses them -> those rows run all 80 iters -> long low-occupancy tail.
// A 4-back-only detector (R10) catches everything but adds +2 iters lag on
// the period-2 majority. Fire on EITHER: both break rules are individually
// verified reference-exact (absmax 0.0 in R12 / R10).
//
// R11 lesson: no single-address returning-atomic ticket (serializes ~200 us).
// R7 lesson: state must fit the launch-bounds cap (WRITE_SIZE is the spill
// tripwire). Solver invariants (R4/R5): real-element v in [0.11,0.92] =>
// upper clip never binds, nu* > 0, s(nu)=sum relu(v-nu) convex
// piecewise-linear => warm-started Newton converges globally & monotonically
// after one step.

template <int CTRL>
__device__ __forceinline__ float dpp_add(float x) {
    int t = __builtin_amdgcn_update_dpp(0, __float_as_int(x), CTRL, 0xf, 0xf, true);
    return x + __int_as_float(t);
}

// Full 64-lane sum -> uniform via readlane(63).
__device__ __forceinline__ float wave_sum(float x) {
    x = dpp_add<0x111>(x);  // row_shr:1
    x = dpp_add<0x112>(x);  // row_shr:2
    x = dpp_add<0x114>(x);  // row_shr:4
    x = dpp_add<0x118>(x);  // row_shr:8
    x = dpp_add<0x142>(x);  // row_bcast:15
    x = dpp_add<0x143>(x);  // row_bcast:31 -> lane63 = total
    return __int_as_float(__builtin_amdgcn_readlane(__float_as_int(x), 63));
}

__global__ __launch_bounds__(64 * ROWS_PER_BLOCK, 8) void pgd_kernel(
        const float* __restrict__ x,
        const int*   __restrict__ y,
        float*       __restrict__ loss) {
    const int lane = threadIdx.x & 63;
    const int row  = blockIdx.x * ROWS_PER_BLOCK + (threadIdx.x >> 6);
    const bool valid15 = lane < (NC - 15 * 64);  // lane < 40 for j==15

    const float* __restrict__ xr = x + (size_t)row * NC;
    const int yv = y[row];            // prefetch: independent, schedules early
    const float flane = (float)(lane + 1);   // checksum weight base

    float cc[EPJ];  // ALPHA * normalized logits (pads: poisoned to -10)
    float v[EPJ];   // pre-projection iterate; p == relu(v - nu)

    // ---- load row + sum of squares (L2 normalize) ----
    float ss = 0.f;
#pragma unroll
    for (int j = 0; j < EPJ; ++j) {
        const int e = j * 64 + lane;
        float xv = (e < NC) ? xr[e] : 0.f;
        cc[j] = xv;
        ss += xv * xv;
    }
    ss = wave_sum(ss);
    const float sc = ALPHA / fmaxf(sqrtf(ss), 1e-12f);
#pragma unroll
    for (int j = 0; j < EPJ; ++j) cc[j] *= sc;
    // Pad poison: v_pad' = 0 + cc_pad + ALN2*D0 ~ -9.65 < 0 every iteration
    // (bitwise constant), so p_pad = 0, never counted in s or m. Lets the hot
    // loop run all 64 lanes unmasked.
    if (!valid15) cc[15] = -10.0f;

    // init so relu(v - nu) == p0 = 0.005 exactly (pads: 0)
#pragma unroll
    for (int j = 0; j < EPJ; ++j) v[j] = KVAL / (float)NC;
    if (!valid15) v[15] = 0.f;
    float nu = 0.f;                  // projection shift for current v
    float nu_m1 = 0.f, nu_m2 = 0.f;  // warm-start history

    // fingerprints: fA = 1 check (2 iters) back, fB = 2 checks (4 iters) back
    float fA_nu = -1.f, fA_c1 = 0.f, fA_c2 = 0.f;  int fA_m = -1;
    float fB_nu = -2.f, fB_c1 = 0.f, fB_c2 = 0.f;  int fB_m = -2;

    for (int it = 0; it < N_ITER; ++it) {
        // ---- ascent: p = relu(v-nu); v' = p + alpha*c + aln2*(log2(1-pc)-log2(pc)) ----
#pragma unroll
        for (int j = 0; j < EPJ; ++j) {
            float pj = fmaxf(v[j] - nu, 0.f);
            float pc = fmaxf(pj, EPS_P);
            float d  = __log2f(1.f - pc) - __log2f(pc);
            v[j] = fmaf(ALN2, d, pj + cc[j]);
        }

        // ---- projection: warm-started Newton on convex s(nu)=K ----
        float nu_new = nu_m2;
        int   m_fin  = 0;
        for (int pass = 0; pass < MAX_SOLVE; ++pass) {
            float s = 0.f;
            int   m = 0;
#pragma unroll
            for (int j = 0; j < EPJ; ++j) {
                float t = v[j] - nu_new;
                s += fmaxf(t, 0.f);
                m += (int)__builtin_popcountll(__ballot(t > 0.f));  // slope
            }
            s = wave_sum(s);
            if (m == 0) { nu_new = 0.f; continue; }  // restart below root (s(0)>K)
            m_fin = m;
            float step = (s - KVAL) / (float)m;
            nu_new += step;
            if (fabsf(step) < 3e-8f) break;          // ~1 ULP: converged
        }
        nu_m2 = nu_m1;
        nu_m1 = nu_new;
        nu    = nu_new;   // p_t == relu(v - nu)

        // ---- period-2/4 fingerprint at odd it (completed count even, like 80) ----
        if (it & 1) {
            float c1 = 0.f, c2 = 0.f;
#pragma unroll
            for (int j = 0; j < EPJ; ++j) {
                c1 = fmaf(v[j], cc[j], c1);
                c2 = fmaf(v[j], flane + (float)(j * 64), c2);
            }
            c1 = wave_sum(c1);
            c2 = wave_sum(c2);
            const bool hit2 = (__float_as_int(nu) == __float_as_int(fA_nu)) &&
                              (m_fin == fA_m) &&
                              (__float_as_int(c1) == __float_as_int(fA_c1)) &&
                              (__float_as_int(c2) == __float_as_int(fA_c2));
            const bool hit4 = (__float_as_int(nu) == __float_as_int(fB_nu)) &&
                              (m_fin == fB_m) &&
                              (__float_as_int(c1) == __float_as_int(fB_c1)) &&
                              (__float_as_int(c2) == __float_as_int(fB_c2));
            fB_nu = fA_nu; fB_m = fA_m; fB_c1 = fA_c1; fB_c2 = fA_c2;
            fA_nu = nu;    fA_m = m_fin; fA_c1 = c1;   fA_c2 = c2;
            if (hit2 || hit4) break;   // state == 2 or 4 iterations back
        }
    }

    // ---- pick p[y] = relu(v[y]-nu), loss = -log(p_y + 1e-8) ----
    const int jy = yv >> 6;
    const int ly = yv & 63;
    float sel = 0.f;
#pragma unroll
    for (int j = 0; j < EPJ; ++j) sel = (j == jy) ? v[j] : sel;
    const float vy = __shfl(sel, ly, 64);
    const float py = fminf(fmaxf(vy - nu, 0.f), 1.f);

    // Unconditional per-row store: no zero-init, no atomics, no memset node.
    if (lane == 0)
        loss[row] = -logf(py + 1e-8f);
}

__global__ void finalize_kernel(const float* __restrict__ loss,
                                float* __restrict__ out) {
    const int t = threadIdx.x;          // 256 threads = 4 waves
    double s = 0.0;
#pragma unroll
    for (int i = 0; i < N_ROWS / 256; ++i)   // 64 coalesced passes
        s += (double)loss[t + 256 * i];
#pragma unroll
    for (int m = 32; m >= 1; m >>= 1) s += __shfl_down(s, m, 64);
    __shared__ double part[4];
    if ((t & 63) == 0) part[t >> 6] = s;
    __syncthreads();
    if (t == 0)
        out[0] = (float)((part[0] + part[1] + part[2] + part[3]) / (double)N_ROWS);
}

extern "C" void kernel_launch(void* const* d_in, const int* in_sizes, int n_in,
                              void* d_out, int out_size, void* d_ws, size_t ws_size,
                              hipStream_t stream) {
    const float* x = (const float*)d_in[0];
    const int*   y = (const int*)d_in[1];
    float* loss = (float*)d_ws;         // 16384 floats = 64 KB of workspace

    pgd_kernel<<<N_ROWS / ROWS_PER_BLOCK, 64 * ROWS_PER_BLOCK, 0, stream>>>(x, y, loss);
    finalize_kernel<<<1, 256, 0, stream>>>(loss, (float*)d_out);
}